// Round 9
// baseline (1188.704 us; speedup 1.0000x reference)
//
#include <hip/hip_runtime.h>
#include <cstddef>

typedef unsigned short ushort_t;
using f32x4  = __attribute__((ext_vector_type(4))) float;
using bf16x8 = __attribute__((ext_vector_type(8))) short;

static constexpr int NX = 100000;
static constexpr int NC = 50000;
static constexpr int E  = 1000000;
static constexpr int E3 = 3 * E;

static constexpr int SHIFT = 6;                     // 64 dst-nodes per bucket
static constexpr int BN = 1 << SHIFT;               // 64
static constexpr int NB = (NX + BN - 1) / BN;       // 1563
static constexpr int CAP = 2304;                    // mean 1920 + 8.8 sigma
static constexpr int PF_CHUNK = 4096;               // edges per partition block
static constexpr int NPF = (E3 + PF_CHUNK - 1) / PF_CHUNK;  // 733
static constexpr int NXT = (NX + 63) / 64;          // 1563
static constexpr int NCT = (NC + 63) / 64;          // 782
static constexpr int AST = 65;                      // acc_T node-stride (bank spread)

__device__ inline ushort_t f2bf(float f) {
    unsigned u = __float_as_uint(f);
    return (ushort_t)((u + 0x7fffu + ((u >> 16) & 1u)) >> 16);   // RNE
}

__device__ inline bf16x8 cvt8(float4 lo, float4 hi) {
    bf16x8 v;
    v[0] = (short)f2bf(lo.x); v[1] = (short)f2bf(lo.y);
    v[2] = (short)f2bf(lo.z); v[3] = (short)f2bf(lo.w);
    v[4] = (short)f2bf(hi.x); v[5] = (short)f2bf(hi.y);
    v[6] = (short)f2bf(hi.z); v[7] = (short)f2bf(hi.w);
    return v;
}

__device__ inline float bfl(unsigned u) { return __uint_as_float(u << 16); }
__device__ inline float bfh(unsigned u) { return __uint_as_float(u & 0xffff0000u); }

// ---------------- MFMA GEMM tile body ----------------
// A-frag: lane l, reg r -> in[row0+16m+(l&15)][ks*32+(l>>4)*8+r]
// B-frag: lane l, reg r -> W [col0+16n+(l&15)][ks*32+(l>>4)*8+r]
// C/D   : col = l&15, row = (l>>4)*4 + reg
__device__ __forceinline__ void gemm_tile(
    const float* __restrict__ in, int nrows, int tile_row0,
    const float* __restrict__ W0, const float* __restrict__ b0, void* __restrict__ o0,
    const float* __restrict__ W1, const float* __restrict__ b1, void* __restrict__ o1,
    const float* __restrict__ W2, const float* __restrict__ b2, void* __restrict__ o2,
    int nlayers, int relu_mask, int bf16_mask)
{
    const int t   = threadIdx.x;
    const int w   = t >> 6;
    const int l   = t & 63;
    const int lr  = l & 15;
    const int lk  = (l >> 4) * 8;
    const int row0 = tile_row0 + (w >> 1) * 32;
    const int col0 = (w & 1) * 32;

    bf16x8 a[2][2];   // [m][ks]
    #pragma unroll
    for (int m = 0; m < 2; ++m) {
        #pragma unroll
        for (int ks = 0; ks < 2; ++ks) {
            const int row = row0 + 16 * m + lr;
            float4 lo = make_float4(0.f, 0.f, 0.f, 0.f), hi = lo;
            if (row < nrows) {
                const float* p = in + (size_t)row * 64 + ks * 32 + lk;
                lo = *reinterpret_cast<const float4*>(p);
                hi = *reinterpret_cast<const float4*>(p + 4);
            }
            a[m][ks] = cvt8(lo, hi);
        }
    }

    for (int ly = 0; ly < nlayers; ++ly) {
        const float* W = (ly == 0) ? W0 : (ly == 1) ? W1 : W2;
        const float* b = (ly == 0) ? b0 : (ly == 1) ? b1 : b2;
        void*        o = (ly == 0) ? o0 : (ly == 1) ? o1 : o2;

        bf16x8 bf[2][2];  // [n][ks]
        float  bias[2];
        #pragma unroll
        for (int n = 0; n < 2; ++n) {
            const int col = col0 + 16 * n + lr;
            bias[n] = b[col];
            #pragma unroll
            for (int ks = 0; ks < 2; ++ks) {
                const float* p = W + (size_t)col * 64 + ks * 32 + lk;
                const float4 lo = *reinterpret_cast<const float4*>(p);
                const float4 hi = *reinterpret_cast<const float4*>(p + 4);
                bf[n][ks] = cvt8(lo, hi);
            }
        }

        f32x4 acc[2][2];
        #pragma unroll
        for (int m = 0; m < 2; ++m)
            #pragma unroll
            for (int n = 0; n < 2; ++n)
                acc[m][n] = (f32x4){0.f, 0.f, 0.f, 0.f};

        #pragma unroll
        for (int m = 0; m < 2; ++m) {
            #pragma unroll
            for (int n = 0; n < 2; ++n) {
                acc[m][n] = __builtin_amdgcn_mfma_f32_16x16x32_bf16(a[m][0], bf[n][0], acc[m][n], 0, 0, 0);
                acc[m][n] = __builtin_amdgcn_mfma_f32_16x16x32_bf16(a[m][1], bf[n][1], acc[m][n], 0, 0, 0);
            }
        }

        const bool relu = (relu_mask >> ly) & 1;
        const bool b16  = (bf16_mask >> ly) & 1;
        #pragma unroll
        for (int m = 0; m < 2; ++m) {
            #pragma unroll
            for (int r = 0; r < 4; ++r) {
                const int row = row0 + 16 * m + (l >> 4) * 4 + r;
                if (row < nrows) {
                    #pragma unroll
                    for (int n = 0; n < 2; ++n) {
                        const int col = col0 + 16 * n + lr;
                        float v = acc[m][n][r] + bias[n];
                        if (relu) v = fmaxf(v, 0.f);
                        if (b16) ((ushort_t*)o)[(size_t)row * 64 + col] = f2bf(v);
                        else     ((float*)o)[(size_t)row * 64 + col] = v;
                    }
                }
            }
        }
    }
}

__global__ __launch_bounds__(256) void zero_bcnt(int* __restrict__ bcnt)
{
    const int i = blockIdx.x * 256 + threadIdx.x;
    if (i < NB) bcnt[i] = 0;
}

// ---- merged: GEMM tiles + edge partition chunks (independent work, one dispatch) ----
// partition: block-aggregated, one global atomic per (block,bucket); bcnt holds COUNTS
// (zeroed before). pk = (src_global << SHIFT) | dst_local, segment base = bucket*CAP.
__global__ __launch_bounds__(256) void gemm_partition(
    const float* __restrict__ x, const float* __restrict__ c,
    const float* __restrict__ Wx, const float* __restrict__ bx, ushort_t* __restrict__ h_self,
    const float* __restrict__ Wff, const float* __restrict__ bff, ushort_t* __restrict__ hff,
    const float* __restrict__ Wbb, const float* __restrict__ bbb, ushort_t* __restrict__ hbb,
    const float* __restrict__ Wc, const float* __restrict__ bc, float* __restrict__ out_c,
    const float* __restrict__ Wcx, const float* __restrict__ bcx, ushort_t* __restrict__ hcx,
    const int* __restrict__ efs, const int* __restrict__ efd,
    const int* __restrict__ ebs, const int* __restrict__ ebd,
    const int* __restrict__ ecs, const int* __restrict__ ecd,
    int* __restrict__ bcnt, unsigned* __restrict__ pk)
{
    __shared__ int h[NB];
    __shared__ int base[NB];
    const int b = blockIdx.x;
    if (b < NXT) {
        gemm_tile(x, NX, b * 64, Wx, bx, h_self, Wff, bff, hff, Wbb, bbb, hbb, 3, 7, 7);
        return;
    }
    if (b < NXT + NCT) {
        gemm_tile(c, NC, (b - NXT) * 64, Wc, bc, out_c, Wcx, bcx, hcx,
                  nullptr, nullptr, nullptr, 2, 3, 2);
        return;
    }
    // partition chunk
    for (int i = threadIdx.x; i < NB; i += 256) h[i] = 0;
    __syncthreads();
    const int e0 = (b - NXT - NCT) * PF_CHUNK;
    unsigned pack[16];
    int buck[16], rank[16];
    #pragma unroll
    for (int i = 0; i < 16; ++i) {
        const int e = e0 + i * 256 + threadIdx.x;
        buck[i] = -1;
        if (e < E3) {
            int d, sg;
            if (e < E)          { d = efd[e];         sg = efs[e]; }
            else if (e < 2 * E) { d = ebs[e - E];     sg = NX + ebd[e - E]; }      // '<-': swap
            else                { d = ecd[e - 2 * E]; sg = 2 * NX + ecs[e - 2 * E]; }
            buck[i] = d >> SHIFT;
            pack[i] = ((unsigned)sg << SHIFT) | (unsigned)(d & (BN - 1));
            rank[i] = atomicAdd(&h[buck[i]], 1);
        }
    }
    __syncthreads();
    for (int bb = threadIdx.x; bb < NB; bb += 256)
        base[bb] = h[bb] ? (bb * CAP + atomicAdd(&bcnt[bb], h[bb])) : 0;
    __syncthreads();
    #pragma unroll
    for (int i = 0; i < 16; ++i)
        if (buck[i] >= 0) {
            const int pos = base[buck[i]] + rank[i];
            if (pos < (buck[i] + 1) * CAP)            // overflow guard (never on this data)
                pk[pos] = pack[i];
        }
}

// ---- gather via LDS f32 atomics into transposed tile + fused pool MFMA ----
// acc_T[feat][node], node-stride 65: ds_add bank = (4*fl + j + dst) % 32 -> ~2-way.
// One quarter-wave (16 lanes) per edge: uint2 (4 feats) per lane. No sort passes.
__global__ __launch_bounds__(256) void gather_atomic_pool(
    const int* __restrict__ bcnt, const unsigned* __restrict__ pk,
    const ushort_t* __restrict__ h_all, const ushort_t* __restrict__ h_self,
    const float* __restrict__ Wp, const float* __restrict__ bp,
    float* __restrict__ out_x)
{
    __shared__ float accT[64 * AST];    // 16.6 KB
    const int b = blockIdx.x;
    const int t = threadIdx.x;
    const int node0 = b * BN;

    {   // init from h_self: thread -> node (t>>2), feats (t&3)*16..+15
        const int nl   = t >> 2;
        const int f0   = (t & 3) * 16;
        const int node = node0 + nl;
        if (node < NX) {
            const uint4 u0 = *reinterpret_cast<const uint4*>(h_self + (size_t)node * 64 + f0);
            const uint4 u1 = *reinterpret_cast<const uint4*>(h_self + (size_t)node * 64 + f0 + 8);
            accT[(f0 +  0) * AST + nl] = bfl(u0.x); accT[(f0 +  1) * AST + nl] = bfh(u0.x);
            accT[(f0 +  2) * AST + nl] = bfl(u0.y); accT[(f0 +  3) * AST + nl] = bfh(u0.y);
            accT[(f0 +  4) * AST + nl] = bfl(u0.z); accT[(f0 +  5) * AST + nl] = bfh(u0.z);
            accT[(f0 +  6) * AST + nl] = bfl(u0.w); accT[(f0 +  7) * AST + nl] = bfh(u0.w);
            accT[(f0 +  8) * AST + nl] = bfl(u1.x); accT[(f0 +  9) * AST + nl] = bfh(u1.x);
            accT[(f0 + 10) * AST + nl] = bfl(u1.y); accT[(f0 + 11) * AST + nl] = bfh(u1.y);
            accT[(f0 + 12) * AST + nl] = bfl(u1.z); accT[(f0 + 13) * AST + nl] = bfh(u1.z);
            accT[(f0 + 14) * AST + nl] = bfl(u1.w); accT[(f0 + 15) * AST + nl] = bfh(u1.w);
        } else {
            #pragma unroll
            for (int k = 0; k < 16; ++k) accT[(f0 + k) * AST + nl] = 0.f;
        }
    }
    __syncthreads();

    int n = bcnt[b]; if (n > CAP) n = CAP;
    const int s    = b * CAP;
    const int tendE = s + n;
    const int qw = t >> 4;               // quarter-wave id 0..15 (one edge each)
    const int fl = t & 15;               // feats fl*4 .. fl*4+3
    const char* hb = reinterpret_cast<const char*>(h_all);

    int e = s + qw;
    for (; e + 48 < tendE; e += 64) {
        const unsigned p0 = pk[e], p1 = pk[e + 16], p2 = pk[e + 32], p3 = pk[e + 48];
        const uint2 u0 = *reinterpret_cast<const uint2*>(hb + ((p0 & ~63u) << 1) + fl * 8);
        const uint2 u1 = *reinterpret_cast<const uint2*>(hb + ((p1 & ~63u) << 1) + fl * 8);
        const uint2 u2 = *reinterpret_cast<const uint2*>(hb + ((p2 & ~63u) << 1) + fl * 8);
        const uint2 u3 = *reinterpret_cast<const uint2*>(hb + ((p3 & ~63u) << 1) + fl * 8);
        float* a0 = &accT[(fl * 4) * AST + (p0 & 63u)];
        float* a1 = &accT[(fl * 4) * AST + (p1 & 63u)];
        float* a2 = &accT[(fl * 4) * AST + (p2 & 63u)];
        float* a3 = &accT[(fl * 4) * AST + (p3 & 63u)];
        atomicAdd(a0,           bfl(u0.x)); atomicAdd(a0 + AST,     bfh(u0.x));
        atomicAdd(a0 + 2 * AST, bfl(u0.y)); atomicAdd(a0 + 3 * AST, bfh(u0.y));
        atomicAdd(a1,           bfl(u1.x)); atomicAdd(a1 + AST,     bfh(u1.x));
        atomicAdd(a1 + 2 * AST, bfl(u1.y)); atomicAdd(a1 + 3 * AST, bfh(u1.y));
        atomicAdd(a2,           bfl(u2.x)); atomicAdd(a2 + AST,     bfh(u2.x));
        atomicAdd(a2 + 2 * AST, bfl(u2.y)); atomicAdd(a2 + 3 * AST, bfh(u2.y));
        atomicAdd(a3,           bfl(u3.x)); atomicAdd(a3 + AST,     bfh(u3.x));
        atomicAdd(a3 + 2 * AST, bfl(u3.y)); atomicAdd(a3 + 3 * AST, bfh(u3.y));
    }
    for (; e < tendE; e += 16) {
        const unsigned p = pk[e];
        const uint2 u = *reinterpret_cast<const uint2*>(hb + ((p & ~63u) << 1) + fl * 8);
        float* a = &accT[(fl * 4) * AST + (p & 63u)];
        atomicAdd(a,           bfl(u.x)); atomicAdd(a + AST,     bfh(u.x));
        atomicAdd(a + 2 * AST, bfl(u.y)); atomicAdd(a + 3 * AST, bfh(u.y));
    }
    __syncthreads();

    // pool: wave w -> cols w*16..+15; A-frag: 8 k-feats of one node from accT (scalar reads)
    const int w = t >> 6, lane = t & 63, q4 = lane >> 4, lr = lane & 15;
    const float* wrow = Wp + (size_t)(w * 16 + lr) * 64;
    const bf16x8 bf0 = cvt8(*reinterpret_cast<const float4*>(wrow + q4 * 8),
                            *reinterpret_cast<const float4*>(wrow + q4 * 8 + 4));
    const bf16x8 bf1 = cvt8(*reinterpret_cast<const float4*>(wrow + 32 + q4 * 8),
                            *reinterpret_cast<const float4*>(wrow + 32 + q4 * 8 + 4));
    const float bias = bp[w * 16 + lr];
    #pragma unroll
    for (int rb = 0; rb < 4; ++rb) {
        const int nl = rb * 16 + lr;
        bf16x8 af0, af1;
        #pragma unroll
        for (int k = 0; k < 8; ++k) {
            af0[k] = (short)f2bf(accT[(q4 * 8 + k) * AST + nl]);
            af1[k] = (short)f2bf(accT[(32 + q4 * 8 + k) * AST + nl]);
        }
        f32x4 acc = (f32x4){0.f, 0.f, 0.f, 0.f};
        acc = __builtin_amdgcn_mfma_f32_16x16x32_bf16(af0, bf0, acc, 0, 0, 0);
        acc = __builtin_amdgcn_mfma_f32_16x16x32_bf16(af1, bf1, acc, 0, 0, 0);
        #pragma unroll
        for (int r = 0; r < 4; ++r) {
            const int row = node0 + rb * 16 + q4 * 4 + r;
            if (row < NX)
                out_x[(size_t)row * 64 + w * 16 + lr] = acc[r] + bias;
        }
    }
}

// ---------------- fallback path ----------------
__global__ __launch_bounds__(256) void fused_linear_mfma(
    const float* __restrict__ in, int nrows,
    const float* __restrict__ W0, const float* __restrict__ b0, void* __restrict__ o0,
    const float* __restrict__ W1, const float* __restrict__ b1, void* __restrict__ o1,
    const float* __restrict__ W2, const float* __restrict__ b2, void* __restrict__ o2,
    int nlayers, int relu_mask, int bf16_mask)
{
    gemm_tile(in, nrows, blockIdx.x * 64, W0, b0, o0, W1, b1, o1, W2, b2, o2,
              nlayers, relu_mask, bf16_mask);
}

__global__ __launch_bounds__(256) void scatter_edges(
    const int* __restrict__ efs, const int* __restrict__ efd,
    const int* __restrict__ ebs, const int* __restrict__ ebd,
    const int* __restrict__ ecs, const int* __restrict__ ecd,
    const ushort_t* __restrict__ h_all, float* __restrict__ agg)
{
    const int idx  = blockIdx.x * 256 + threadIdx.x;
    const int lane = idx & 63;
    const int e    = idx >> 6;
    if (e >= E3) return;
    int src, dst;
    if (e < E)          { src = efs[e];           dst = efd[e]; }
    else if (e < 2 * E) { src = NX + ebd[e - E];  dst = ebs[e - E]; }
    else                { src = 2 * NX + ecs[e - 2 * E]; dst = ecd[e - 2 * E]; }
    const unsigned u = (unsigned)h_all[(size_t)src * 64 + lane] << 16;
    atomicAdd(&agg[(size_t)dst * 64 + lane], __uint_as_float(u));
}

extern "C" void kernel_launch(void* const* d_in, const int* in_sizes, int n_in,
                              void* d_out, int out_size, void* d_ws, size_t ws_size,
                              hipStream_t stream)
{
    const float* x   = (const float*)d_in[0];
    const float* c   = (const float*)d_in[1];
    const int*   efs = (const int*)d_in[2];
    const int*   efd = (const int*)d_in[3];
    const int*   ebs = (const int*)d_in[4];
    const int*   ebd = (const int*)d_in[5];
    const int*   ecs = (const int*)d_in[6];
    const int*   ecd = (const int*)d_in[7];
    const float* Wx  = (const float*)d_in[8];
    const float* bx  = (const float*)d_in[9];
    const float* Wc  = (const float*)d_in[10];
    const float* bc  = (const float*)d_in[11];
    const float* Wff = (const float*)d_in[12];
    const float* bff = (const float*)d_in[13];
    const float* Wbb = (const float*)d_in[14];
    const float* bbb = (const float*)d_in[15];
    const float* Wcx = (const float*)d_in[16];
    const float* bcx = (const float*)d_in[17];
    const float* Wp  = (const float*)d_in[18];
    const float* bp  = (const float*)d_in[19];

    float* out_x = (float*)d_out;                    // [NX*64]
    float* out_c = (float*)d_out + (size_t)NX * 64;  // [NC*64]

    // ws layout: bf16 h tables (ff, bb, cx, self), bcnt, pk
    ushort_t* h_all  = (ushort_t*)d_ws;
    ushort_t* hff    = h_all;
    ushort_t* hbb    = h_all + (size_t)NX * 64;
    ushort_t* hcx    = h_all + (size_t)2 * NX * 64;
    ushort_t* h_self = h_all + (size_t)(2 * NX + NC) * 64;
    const size_t h_elems = (size_t)(3 * NX + NC) * 64;        // 44.8 MB

    int* bcnt    = (int*)(h_all + h_elems);                   // NB (counts)
    unsigned* pk = (unsigned*)(bcnt + NB);                    // NB*CAP = 14.4 MB
    const size_t need_bytes = h_elems * 2 + (size_t)NB * 4 + (size_t)NB * CAP * 4;

    if (ws_size >= need_bytes) {
        zero_bcnt<<<(NB + 255) / 256, 256, 0, stream>>>(bcnt);
        gemm_partition<<<NXT + NCT + NPF, 256, 0, stream>>>(
            x, c, Wx, bx, h_self, Wff, bff, hff, Wbb, bbb, hbb,
            Wc, bc, out_c, Wcx, bcx, hcx,
            efs, efd, ebs, ebd, ecs, ecd, bcnt, pk);
        gather_atomic_pool<<<NB, 256, 0, stream>>>(
            bcnt, pk, h_all, h_self, Wp, bp, out_x);
    } else {
        // fallback: self_x f32 into out_x, per-edge atomics, standalone pool
        fused_linear_mfma<<<NXT, 256, 0, stream>>>(
            x, NX, Wx, bx, out_x, Wff, bff, hff, Wbb, bbb, hbb, 3, 7, 6);
        fused_linear_mfma<<<NCT, 256, 0, stream>>>(
            c, NC, Wc, bc, out_c, Wcx, bcx, hcx, nullptr, nullptr, nullptr, 2, 3, 2);
        scatter_edges<<<((size_t)E3 * 64 + 255) / 256, 256, 0, stream>>>(
            efs, efd, ebs, ebd, ecs, ecd, h_all, out_x);
        fused_linear_mfma<<<NXT, 256, 0, stream>>>(
            out_x, NX, Wp, bp, out_x, nullptr, nullptr, nullptr, nullptr, nullptr, nullptr, 1, 0, 0);
    }
}

// Round 10
// 146.996 us; speedup vs baseline: 8.0866x; 8.0866x over previous
//
#include <hip/hip_runtime.h>
#include <cstddef>

typedef unsigned short ushort_t;
using f32x4  = __attribute__((ext_vector_type(4))) float;
using bf16x8 = __attribute__((ext_vector_type(8))) short;

static constexpr int NX = 100000;
static constexpr int NC = 50000;
static constexpr int E  = 1000000;
static constexpr int E3 = 3 * E;

static constexpr int SHIFT = 6;                     // 64 dst-nodes per bucket
static constexpr int BN = 1 << SHIFT;               // 64
static constexpr int NB = (NX + BN - 1) / BN;       // 1563
static constexpr int CAP = 2304;                    // mean 1920 + 8.8 sigma
static constexpr int PF_CHUNK = 4096;               // edges per partition block
static constexpr int NPF = (E3 + PF_CHUNK - 1) / PF_CHUNK;  // 733
static constexpr int NXT = (NX + 63) / 64;          // 1563
static constexpr int NCT = (NC + 63) / 64;          // 782

__device__ inline ushort_t f2bf(float f) {
    unsigned u = __float_as_uint(f);
    return (ushort_t)((u + 0x7fffu + ((u >> 16) & 1u)) >> 16);   // RNE
}

__device__ inline bf16x8 cvt8(float4 lo, float4 hi) {
    bf16x8 v;
    v[0] = (short)f2bf(lo.x); v[1] = (short)f2bf(lo.y);
    v[2] = (short)f2bf(lo.z); v[3] = (short)f2bf(lo.w);
    v[4] = (short)f2bf(hi.x); v[5] = (short)f2bf(hi.y);
    v[6] = (short)f2bf(hi.z); v[7] = (short)f2bf(hi.w);
    return v;
}

__device__ inline float bfl(unsigned u) { return __uint_as_float(u << 16); }
__device__ inline float bfh(unsigned u) { return __uint_as_float(u & 0xffff0000u); }

// ---------------- MFMA GEMM tile body ----------------
// A-frag: lane l, reg r -> in[row0+16m+(l&15)][ks*32+(l>>4)*8+r]
// B-frag: lane l, reg r -> W [col0+16n+(l&15)][ks*32+(l>>4)*8+r]
// C/D   : col = l&15, row = (l>>4)*4 + reg
__device__ __forceinline__ void gemm_tile(
    const float* __restrict__ in, int nrows, int tile_row0,
    const float* __restrict__ W0, const float* __restrict__ b0, void* __restrict__ o0,
    const float* __restrict__ W1, const float* __restrict__ b1, void* __restrict__ o1,
    const float* __restrict__ W2, const float* __restrict__ b2, void* __restrict__ o2,
    int nlayers, int relu_mask, int bf16_mask)
{
    const int t   = threadIdx.x;
    const int w   = t >> 6;
    const int l   = t & 63;
    const int lr  = l & 15;
    const int lk  = (l >> 4) * 8;
    const int row0 = tile_row0 + (w >> 1) * 32;
    const int col0 = (w & 1) * 32;

    bf16x8 a[2][2];   // [m][ks]
    #pragma unroll
    for (int m = 0; m < 2; ++m) {
        #pragma unroll
        for (int ks = 0; ks < 2; ++ks) {
            const int row = row0 + 16 * m + lr;
            float4 lo = make_float4(0.f, 0.f, 0.f, 0.f), hi = lo;
            if (row < nrows) {
                const float* p = in + (size_t)row * 64 + ks * 32 + lk;
                lo = *reinterpret_cast<const float4*>(p);
                hi = *reinterpret_cast<const float4*>(p + 4);
            }
            a[m][ks] = cvt8(lo, hi);
        }
    }

    for (int ly = 0; ly < nlayers; ++ly) {
        const float* W = (ly == 0) ? W0 : (ly == 1) ? W1 : W2;
        const float* b = (ly == 0) ? b0 : (ly == 1) ? b1 : b2;
        void*        o = (ly == 0) ? o0 : (ly == 1) ? o1 : o2;

        bf16x8 bf[2][2];  // [n][ks]
        float  bias[2];
        #pragma unroll
        for (int n = 0; n < 2; ++n) {
            const int col = col0 + 16 * n + lr;
            bias[n] = b[col];
            #pragma unroll
            for (int ks = 0; ks < 2; ++ks) {
                const float* p = W + (size_t)col * 64 + ks * 32 + lk;
                const float4 lo = *reinterpret_cast<const float4*>(p);
                const float4 hi = *reinterpret_cast<const float4*>(p + 4);
                bf[n][ks] = cvt8(lo, hi);
            }
        }

        f32x4 acc[2][2];
        #pragma unroll
        for (int m = 0; m < 2; ++m)
            #pragma unroll
            for (int n = 0; n < 2; ++n)
                acc[m][n] = (f32x4){0.f, 0.f, 0.f, 0.f};

        #pragma unroll
        for (int m = 0; m < 2; ++m) {
            #pragma unroll
            for (int n = 0; n < 2; ++n) {
                acc[m][n] = __builtin_amdgcn_mfma_f32_16x16x32_bf16(a[m][0], bf[n][0], acc[m][n], 0, 0, 0);
                acc[m][n] = __builtin_amdgcn_mfma_f32_16x16x32_bf16(a[m][1], bf[n][1], acc[m][n], 0, 0, 0);
            }
        }

        const bool relu = (relu_mask >> ly) & 1;
        const bool b16  = (bf16_mask >> ly) & 1;
        #pragma unroll
        for (int m = 0; m < 2; ++m) {
            #pragma unroll
            for (int r = 0; r < 4; ++r) {
                const int row = row0 + 16 * m + (l >> 4) * 4 + r;
                if (row < nrows) {
                    #pragma unroll
                    for (int n = 0; n < 2; ++n) {
                        const int col = col0 + 16 * n + lr;
                        float v = acc[m][n][r] + bias[n];
                        if (relu) v = fmaxf(v, 0.f);
                        if (b16) ((ushort_t*)o)[(size_t)row * 64 + col] = f2bf(v);
                        else     ((float*)o)[(size_t)row * 64 + col] = v;
                    }
                }
            }
        }
    }
}

// ---- merged: edge-partition chunks first (latency-bound), then GEMM tiles ----
// partition: block-aggregated single-pass, one global atomic per (block,bucket);
// bcnt holds COUNTS (memset to 0 before). pk = (src_global << SHIFT) | dst_local,
// segment base = bucket*CAP.
__global__ __launch_bounds__(256) void gemm_partition(
    const float* __restrict__ x, const float* __restrict__ c,
    const float* __restrict__ Wx, const float* __restrict__ bx, ushort_t* __restrict__ h_self,
    const float* __restrict__ Wff, const float* __restrict__ bff, ushort_t* __restrict__ hff,
    const float* __restrict__ Wbb, const float* __restrict__ bbb, ushort_t* __restrict__ hbb,
    const float* __restrict__ Wc, const float* __restrict__ bc, float* __restrict__ out_c,
    const float* __restrict__ Wcx, const float* __restrict__ bcx, ushort_t* __restrict__ hcx,
    const int* __restrict__ efs, const int* __restrict__ efd,
    const int* __restrict__ ebs, const int* __restrict__ ebd,
    const int* __restrict__ ecs, const int* __restrict__ ecd,
    int* __restrict__ bcnt, unsigned* __restrict__ pk)
{
    __shared__ int h[NB];
    __shared__ int base[NB];
    const int b = blockIdx.x;
    if (b >= NPF) {
        const int gb = b - NPF;
        if (gb < NXT)
            gemm_tile(x, NX, gb * 64, Wx, bx, h_self, Wff, bff, hff, Wbb, bbb, hbb, 3, 7, 7);
        else
            gemm_tile(c, NC, (gb - NXT) * 64, Wc, bc, out_c, Wcx, bcx, hcx,
                      nullptr, nullptr, nullptr, 2, 3, 2);
        return;
    }
    // partition chunk
    for (int i = threadIdx.x; i < NB; i += 256) h[i] = 0;
    __syncthreads();
    const int e0 = b * PF_CHUNK;
    unsigned pack[16];
    int buck[16], rank[16];
    #pragma unroll
    for (int i = 0; i < 16; ++i) {
        const int e = e0 + i * 256 + threadIdx.x;
        buck[i] = -1;
        if (e < E3) {
            int d, sg;
            if (e < E)          { d = efd[e];         sg = efs[e]; }
            else if (e < 2 * E) { d = ebs[e - E];     sg = NX + ebd[e - E]; }      // '<-': swap
            else                { d = ecd[e - 2 * E]; sg = 2 * NX + ecs[e - 2 * E]; }
            buck[i] = d >> SHIFT;
            pack[i] = ((unsigned)sg << SHIFT) | (unsigned)(d & (BN - 1));
            rank[i] = atomicAdd(&h[buck[i]], 1);
        }
    }
    __syncthreads();
    for (int bb = threadIdx.x; bb < NB; bb += 256)
        base[bb] = h[bb] ? (bb * CAP + atomicAdd(&bcnt[bb], h[bb])) : 0;
    __syncthreads();
    #pragma unroll
    for (int i = 0; i < 16; ++i)
        if (buck[i] >= 0) {
            const int pos = base[buck[i]] + rank[i];
            if (pos < (buck[i] + 1) * CAP)            // overflow guard (never on this data)
                pk[pos] = pack[i];
        }
}

// One block per 64-node bucket: LDS counting sort -> srt (byte offsets into h_all),
// eighth-wave gather (8 lanes x uint4 = one 128B row per edge), LDS bf16 agg tile,
// fused pool MFMA.
__global__ __launch_bounds__(256) void sort_gather_pool(
    const int* __restrict__ bcnt, const unsigned* __restrict__ pk,
    const ushort_t* __restrict__ h_all, const ushort_t* __restrict__ h_self,
    const float* __restrict__ Wp, const float* __restrict__ bp,
    float* __restrict__ out_x)
{
    __shared__ unsigned srt[CAP];
    __shared__ int cnt[BN], nstart[BN], cur[BN];
    __shared__ ushort_t agg_lds[BN * 72];   // row stride 144 B

    const int b = blockIdx.x;
    const int t = threadIdx.x;
    const int s = b * CAP;
    int n = bcnt[b]; if (n > CAP) n = CAP;
    const int tend = s + n;

    if (t < BN) cnt[t] = 0;
    __syncthreads();
    for (int e = s + t; e < tend; e += 256)
        atomicAdd(&cnt[pk[e] & (BN - 1)], 1);
    __syncthreads();
    if (t < BN) {                         // wave 0: shfl inclusive scan over 64
        const int v = cnt[t];
        int xs = v;
        #pragma unroll
        for (int d = 1; d < BN; d <<= 1) {
            const int y = __shfl_up(xs, d, 64);
            if (t >= d) xs += y;
        }
        nstart[t] = xs - v;
        cur[t]    = xs - v;
    }
    __syncthreads();
    for (int e = s + t; e < tend; e += 256) {
        const unsigned p = pk[e];
        const int pos = atomicAdd(&cur[p & (BN - 1)], 1);
        srt[pos] = (p & ~(unsigned)(BN - 1)) << 1;   // src_global * 128 (byte offset)
    }
    __syncthreads();

    const int w    = t >> 6;
    const int lane = t & 63;
    const int g    = lane >> 3;          // eighth-wave id 0..7 (one edge each)
    const int fl   = lane & 7;           // features fl*8 .. fl*8+7 (16 B)
    const unsigned foff = fl * 16;       // byte offset within 128B row
    const int node0 = b * BN;
    const char* hb = reinterpret_cast<const char*>(h_all);
    const char* hs = reinterpret_cast<const char*>(h_self);

    for (int i = 0; i < 16; ++i) {
        const int nl   = w * 16 + i;
        const int node = node0 + nl;
        const int start = nstart[nl];
        const int count = cnt[nl];
        float a0 = 0.f, a1 = 0.f, a2 = 0.f, a3 = 0.f;
        float a4 = 0.f, a5 = 0.f, a6 = 0.f, a7 = 0.f;
        if (g == 0 && node < NX) {
            const uint4 u = *reinterpret_cast<const uint4*>(hs + (size_t)node * 128 + foff);
            a0 = bfl(u.x); a1 = bfh(u.x); a2 = bfl(u.y); a3 = bfh(u.y);
            a4 = bfl(u.z); a5 = bfh(u.z); a6 = bfl(u.w); a7 = bfh(u.w);
        }
        int e = g;
        for (; e + 24 < count; e += 32) {
            const unsigned o0 = srt[start + e]      + foff;
            const unsigned o1 = srt[start + e + 8]  + foff;
            const unsigned o2 = srt[start + e + 16] + foff;
            const unsigned o3 = srt[start + e + 24] + foff;
            const uint4 u0 = *reinterpret_cast<const uint4*>(hb + o0);
            const uint4 u1 = *reinterpret_cast<const uint4*>(hb + o1);
            const uint4 u2 = *reinterpret_cast<const uint4*>(hb + o2);
            const uint4 u3 = *reinterpret_cast<const uint4*>(hb + o3);
            a0 += bfl(u0.x) + bfl(u1.x) + bfl(u2.x) + bfl(u3.x);
            a1 += bfh(u0.x) + bfh(u1.x) + bfh(u2.x) + bfh(u3.x);
            a2 += bfl(u0.y) + bfl(u1.y) + bfl(u2.y) + bfl(u3.y);
            a3 += bfh(u0.y) + bfh(u1.y) + bfh(u2.y) + bfh(u3.y);
            a4 += bfl(u0.z) + bfl(u1.z) + bfl(u2.z) + bfl(u3.z);
            a5 += bfh(u0.z) + bfh(u1.z) + bfh(u2.z) + bfh(u3.z);
            a6 += bfl(u0.w) + bfl(u1.w) + bfl(u2.w) + bfl(u3.w);
            a7 += bfh(u0.w) + bfh(u1.w) + bfh(u2.w) + bfh(u3.w);
        }
        for (; e < count; e += 8) {
            const uint4 u = *reinterpret_cast<const uint4*>(hb + (srt[start + e] + foff));
            a0 += bfl(u.x); a1 += bfh(u.x); a2 += bfl(u.y); a3 += bfh(u.y);
            a4 += bfl(u.z); a5 += bfh(u.z); a6 += bfl(u.w); a7 += bfh(u.w);
        }
        a0 += __shfl_xor(a0, 8); a0 += __shfl_xor(a0, 16); a0 += __shfl_xor(a0, 32);
        a1 += __shfl_xor(a1, 8); a1 += __shfl_xor(a1, 16); a1 += __shfl_xor(a1, 32);
        a2 += __shfl_xor(a2, 8); a2 += __shfl_xor(a2, 16); a2 += __shfl_xor(a2, 32);
        a3 += __shfl_xor(a3, 8); a3 += __shfl_xor(a3, 16); a3 += __shfl_xor(a3, 32);
        a4 += __shfl_xor(a4, 8); a4 += __shfl_xor(a4, 16); a4 += __shfl_xor(a4, 32);
        a5 += __shfl_xor(a5, 8); a5 += __shfl_xor(a5, 16); a5 += __shfl_xor(a5, 32);
        a6 += __shfl_xor(a6, 8); a6 += __shfl_xor(a6, 16); a6 += __shfl_xor(a6, 32);
        a7 += __shfl_xor(a7, 8); a7 += __shfl_xor(a7, 16); a7 += __shfl_xor(a7, 32);
        if (lane < 8) {
            uint4 pck;
            pck.x = ((unsigned)f2bf(a1) << 16) | (unsigned)f2bf(a0);
            pck.y = ((unsigned)f2bf(a3) << 16) | (unsigned)f2bf(a2);
            pck.z = ((unsigned)f2bf(a5) << 16) | (unsigned)f2bf(a4);
            pck.w = ((unsigned)f2bf(a7) << 16) | (unsigned)f2bf(a6);
            *reinterpret_cast<uint4*>(&agg_lds[nl * 72 + fl * 8]) = pck;
        }
    }
    __syncthreads();

    // pool: wave w -> cols w*16..w*16+15 over all 64 rows (4 row-tiles x 2 MFMA)
    const int lr = lane & 15, q4 = lane >> 4;
    const float* wrow = Wp + (size_t)(w * 16 + lr) * 64;
    const bf16x8 bf0 = cvt8(*reinterpret_cast<const float4*>(wrow + q4 * 8),
                            *reinterpret_cast<const float4*>(wrow + q4 * 8 + 4));
    const bf16x8 bf1 = cvt8(*reinterpret_cast<const float4*>(wrow + 32 + q4 * 8),
                            *reinterpret_cast<const float4*>(wrow + 32 + q4 * 8 + 4));
    const float bias = bp[w * 16 + lr];
    #pragma unroll
    for (int rb = 0; rb < 4; ++rb) {
        const bf16x8 af0 = *reinterpret_cast<const bf16x8*>(&agg_lds[(rb * 16 + lr) * 72 + q4 * 8]);
        const bf16x8 af1 = *reinterpret_cast<const bf16x8*>(&agg_lds[(rb * 16 + lr) * 72 + 32 + q4 * 8]);
        f32x4 acc = (f32x4){0.f, 0.f, 0.f, 0.f};
        acc = __builtin_amdgcn_mfma_f32_16x16x32_bf16(af0, bf0, acc, 0, 0, 0);
        acc = __builtin_amdgcn_mfma_f32_16x16x32_bf16(af1, bf1, acc, 0, 0, 0);
        #pragma unroll
        for (int r = 0; r < 4; ++r) {
            const int row = node0 + rb * 16 + q4 * 4 + r;
            if (row < NX)
                out_x[(size_t)row * 64 + w * 16 + lr] = acc[r] + bias;
        }
    }
}

// ---------------- fallback path ----------------
__global__ __launch_bounds__(256) void fused_linear_mfma(
    const float* __restrict__ in, int nrows,
    const float* __restrict__ W0, const float* __restrict__ b0, void* __restrict__ o0,
    const float* __restrict__ W1, const float* __restrict__ b1, void* __restrict__ o1,
    const float* __restrict__ W2, const float* __restrict__ b2, void* __restrict__ o2,
    int nlayers, int relu_mask, int bf16_mask)
{
    gemm_tile(in, nrows, blockIdx.x * 64, W0, b0, o0, W1, b1, o1, W2, b2, o2,
              nlayers, relu_mask, bf16_mask);
}

__global__ __launch_bounds__(256) void scatter_edges(
    const int* __restrict__ efs, const int* __restrict__ efd,
    const int* __restrict__ ebs, const int* __restrict__ ebd,
    const int* __restrict__ ecs, const int* __restrict__ ecd,
    const ushort_t* __restrict__ h_all, float* __restrict__ agg)
{
    const int idx  = blockIdx.x * 256 + threadIdx.x;
    const int lane = idx & 63;
    const int e    = idx >> 6;
    if (e >= E3) return;
    int src, dst;
    if (e < E)          { src = efs[e];           dst = efd[e]; }
    else if (e < 2 * E) { src = NX + ebd[e - E];  dst = ebs[e - E]; }
    else                { src = 2 * NX + ecs[e - 2 * E]; dst = ecd[e - 2 * E]; }
    const unsigned u = (unsigned)h_all[(size_t)src * 64 + lane] << 16;
    atomicAdd(&agg[(size_t)dst * 64 + lane], __uint_as_float(u));
}

extern "C" void kernel_launch(void* const* d_in, const int* in_sizes, int n_in,
                              void* d_out, int out_size, void* d_ws, size_t ws_size,
                              hipStream_t stream)
{
    const float* x   = (const float*)d_in[0];
    const float* c   = (const float*)d_in[1];
    const int*   efs = (const int*)d_in[2];
    const int*   efd = (const int*)d_in[3];
    const int*   ebs = (const int*)d_in[4];
    const int*   ebd = (const int*)d_in[5];
    const int*   ecs = (const int*)d_in[6];
    const int*   ecd = (const int*)d_in[7];
    const float* Wx  = (const float*)d_in[8];
    const float* bx  = (const float*)d_in[9];
    const float* Wc  = (const float*)d_in[10];
    const float* bc  = (const float*)d_in[11];
    const float* Wff = (const float*)d_in[12];
    const float* bff = (const float*)d_in[13];
    const float* Wbb = (const float*)d_in[14];
    const float* bbb = (const float*)d_in[15];
    const float* Wcx = (const float*)d_in[16];
    const float* bcx = (const float*)d_in[17];
    const float* Wp  = (const float*)d_in[18];
    const float* bp  = (const float*)d_in[19];

    float* out_x = (float*)d_out;                    // [NX*64]
    float* out_c = (float*)d_out + (size_t)NX * 64;  // [NC*64]

    // ws layout: bf16 h tables (ff, bb, cx, self), bcnt, pk
    ushort_t* h_all  = (ushort_t*)d_ws;
    ushort_t* hff    = h_all;
    ushort_t* hbb    = h_all + (size_t)NX * 64;
    ushort_t* hcx    = h_all + (size_t)2 * NX * 64;
    ushort_t* h_self = h_all + (size_t)(2 * NX + NC) * 64;
    const size_t h_elems = (size_t)(3 * NX + NC) * 64;        // 44.8 MB

    int* bcnt    = (int*)(h_all + h_elems);                   // NB (counts)
    unsigned* pk = (unsigned*)(bcnt + NB);                    // NB*CAP = 14.4 MB
    const size_t need_bytes = h_elems * 2 + (size_t)NB * 4 + (size_t)NB * CAP * 4;

    if (ws_size >= need_bytes) {
        hipMemsetAsync(bcnt, 0, (size_t)NB * sizeof(int), stream);
        gemm_partition<<<NPF + NXT + NCT, 256, 0, stream>>>(
            x, c, Wx, bx, h_self, Wff, bff, hff, Wbb, bbb, hbb,
            Wc, bc, out_c, Wcx, bcx, hcx,
            efs, efd, ebs, ebd, ecs, ecd, bcnt, pk);
        sort_gather_pool<<<NB, 256, 0, stream>>>(
            bcnt, pk, h_all, h_self, Wp, bp, out_x);
    } else {
        // fallback: self_x f32 into out_x, per-edge atomics, standalone pool
        fused_linear_mfma<<<NXT, 256, 0, stream>>>(
            x, NX, Wx, bx, out_x, Wff, bff, hff, Wbb, bbb, hbb, 3, 7, 6);
        fused_linear_mfma<<<NCT, 256, 0, stream>>>(
            c, NC, Wc, bc, out_c, Wcx, bcx, hcx, nullptr, nullptr, nullptr, 2, 3, 2);
        scatter_edges<<<((size_t)E3 * 64 + 255) / 256, 256, 0, stream>>>(
            efs, efd, ebs, ebd, ecs, ecd, h_all, out_x);
        fused_linear_mfma<<<NXT, 256, 0, stream>>>(
            out_x, NX, Wp, bp, out_x, nullptr, nullptr, nullptr, nullptr, nullptr, nullptr, 1, 0, 0);
    }
}